// Round 14
// baseline (292.917 us; speedup 1.0000x reference)
//
#include <hip/hip_runtime.h>
#include <math.h>

#define N_NODES 32768
#define N_FEAT 256
#define HID 256
#define N_GRAPHS 64
#define NPG 512
#define N_CLASSES 4
#define BN_EPS 1e-5f

typedef __attribute__((ext_vector_type(8))) short bf16x8;
typedef __attribute__((ext_vector_type(4))) float f32x4;

__device__ __forceinline__ ushort f2b(float f) {
    union { float f; uint u; } v; v.f = f;
    uint u = v.u;
    return (ushort)((u + 0x7FFFu + ((u >> 16) & 1u)) >> 16);   // RNE
}
__device__ __forceinline__ float bflo(uint u) {
    union { uint u; float f; } v; v.u = u << 16;
    return v.f;
}
__device__ __forceinline__ float bfhi(uint u) {
    union { uint u; float f; } v; v.u = u & 0xFFFF0000u;
    return v.f;
}

// ---------------- fused: degree count + x->bf16 + W transpose + csr sentinel init ----------------
__global__ void k_count_prep(const int* __restrict__ dst, int* __restrict__ degcnt, int cntB,
                             const float* __restrict__ x, ushort* __restrict__ xb, int xB,
                             const float* __restrict__ W1, const float* __restrict__ W2,
                             ushort* __restrict__ Wt1, ushort* __restrict__ Wt2,
                             uint* __restrict__ csrs, int E) {
    int b = blockIdx.x;
    int t = threadIdx.x;
    if (b < cntB) {
        int e = b * 256 + t;
        if (e < E) atomicAdd(&degcnt[dst[e]], 1);
    } else if (b < cntB + xB) {
        int i = (b - cntB) * 256 + t;
        float4 v0 = *(const float4*)(x + (size_t)i * 8);
        float4 v1 = *(const float4*)(x + (size_t)i * 8 + 4);
        uint4 o;
        o.x = (uint)f2b(v0.x) | ((uint)f2b(v0.y) << 16);
        o.y = (uint)f2b(v0.z) | ((uint)f2b(v0.w) << 16);
        o.z = (uint)f2b(v1.x) | ((uint)f2b(v1.y) << 16);
        o.w = (uint)f2b(v1.z) | ((uint)f2b(v1.w) << 16);
        *(uint4*)(xb + (size_t)i * 8) = o;
    } else if (b < cntB + xB + 512) {
        int wb = b - cntB - xB;
        const float* W = (wb < 256) ? W1 : W2;
        ushort* Wt = (wb < 256) ? Wt1 : Wt2;
        int n = wb & 255;
        Wt[n * 256 + t] = f2b(W[t * 256 + n]);
    } else {
        int i = (b - cntB - xB - 512) * 256 + t;
        uint4 s = make_uint4(N_NODES, N_NODES, N_NODES, N_NODES);
        *(uint4*)(csrs + (size_t)i * 4) = s;
    }
}

// ---------------- 2-phase scan ----------------
// phase 1: per-block (256 nodes) padded-degree sums; block 0 zeroes the pad row
__global__ __launch_bounds__(256) void k_scan1(const int* __restrict__ degcnt,
                                               int* __restrict__ blocksum,
                                               ushort* __restrict__ hs_pad) {
    int n = blockIdx.x * 256 + threadIdx.x;
    int p = (degcnt[n] + 2) & ~1;
#pragma unroll
    for (int off = 1; off < 64; off <<= 1) p += __shfl_xor(p, off);
    __shared__ int ws[4];
    int lane = threadIdx.x & 63, w = threadIdx.x >> 6;
    if (lane == 0) ws[w] = p;
    __syncthreads();
    if (threadIdx.x == 0)
        blocksum[blockIdx.x] = ws[0] + ws[1] + ws[2] + ws[3];
    if (blockIdx.x == 0 && threadIdx.x < 128)
        ((uint*)hs_pad)[threadIdx.x] = 0;
}

// phase 2: per-node run offsets (each block redundantly prefixes the 128 block sums),
// self entries, cursor, dinv, sentinel
__global__ __launch_bounds__(256) void k_scan3(const int* __restrict__ degcnt,
                                               const int* __restrict__ blocksum,
                                               float* __restrict__ dinv,
                                               int* __restrict__ row_start,
                                               int* __restrict__ cursor,
                                               uint* __restrict__ csrs) {
    __shared__ int bs[128];
    __shared__ int ws[4];
    int t = threadIdx.x;
    if (t < 128) bs[t] = blocksum[t];
    int n = blockIdx.x * 256 + t;
    int c = degcnt[n];
    int p = (c + 2) & ~1;
    int lane = t & 63, w = t >> 6;
    int inc = p;
#pragma unroll
    for (int off = 1; off < 64; off <<= 1) {
        int u = __shfl_up(inc, off);
        if (lane >= off) inc += u;
    }
    if (lane == 63) ws[w] = inc;
    __syncthreads();
    int boff = 0;
    for (int i = 0; i < blockIdx.x; ++i) boff += bs[i];   // LDS broadcast reads
    int wadd = 0;
    for (int i = 0; i < w; ++i) wadd += ws[i];
    int run = boff + wadd + inc - p;
    row_start[n] = run;
    csrs[run] = (uint)n;
    cursor[n] = run + 1;
    dinv[n] = rsqrtf((float)(c + 1));
    if (blockIdx.x == 127 && t == 255) row_start[N_NODES] = run + p;
}

// ---------------- fill CSR (append after self) ----------------
__global__ void k_fill(const int* __restrict__ src, const int* __restrict__ dst,
                       int* __restrict__ cursor, uint* __restrict__ csrs, int E) {
    int e = blockIdx.x * 256 + threadIdx.x;
    if (e >= E) return;
    int d = dst[e];
    int pos = atomicAdd(&cursor[d], 1);
    csrs[pos] = (uint)src[e];
}

// ---------------- bf16 MFMA GEMM, B staged in LDS (swizzled); optional fused BN on A ----------------
// hs[row][256] = dinv[row]*(A @ Bt^T). Block: 512 thr / 8 waves 2x4, tile 128x128. Grid (2, 256).
template <bool BN_A>
__device__ __forceinline__ void gemm_body(const ushort* __restrict__ A,
                                          const ushort* __restrict__ Bt,
                                          const float* __restrict__ dinv,
                                          const float* __restrict__ bnsum,
                                          const float* __restrict__ bnsq,
                                          const float* __restrict__ gamma,
                                          const float* __restrict__ beta,
                                          ushort* __restrict__ hs) {
    __shared__ ushort Bs[128 * 256];      // 64 KB
    __shared__ float2 bnc[256];           // 2 KB (sc, sh)
    int tid = threadIdx.x;                // 0..511
    int n0 = blockIdx.x * 128;
    int m0 = blockIdx.y * 128;

    if (BN_A && tid < 256) {
        const float invN = 1.0f / (float)N_NODES;
        float mean = bnsum[tid] * invN;
        float var = bnsq[tid] * invN - mean * mean;
        float sc = rsqrtf(var + BN_EPS) * gamma[tid];
        bnc[tid] = make_float2(sc, beta[tid] - mean * sc);
    }

#pragma unroll
    for (int c = 0; c < 8; ++c) {
        int g = c * 512 + tid;
        int idx = g * 8;
        int row = idx >> 8;
        int col = idx & 255;
        uint4 v = *(const uint4*)(Bt + (size_t)(n0 + row) * 256 + col);
        int sidx = idx ^ ((row & 7) << 3);
        *(uint4*)(Bs + sidx) = v;
    }
    __syncthreads();

    int wid = tid >> 6;
    int lane = tid & 63;
    int wr = wid >> 2, wc = wid & 3;      // 2 row-groups x 4 col-groups
    int r = lane & 15;
    int ko = (lane >> 4) * 8;

    const ushort* Ab = A + (size_t)(m0 + wr * 64 + r) * 256 + ko;

    f32x4 acc[4][2] = {};
#pragma unroll
    for (int ks = 0; ks < 8; ++ks) {
        bf16x8 a[4], b[2];
        if (BN_A) {
            int kb = ko + ks * 32;
            float2 c0 = bnc[kb + 0], c1 = bnc[kb + 1], c2 = bnc[kb + 2], c3 = bnc[kb + 3];
            float2 c4 = bnc[kb + 4], c5 = bnc[kb + 5], c6 = bnc[kb + 6], c7 = bnc[kb + 7];
#pragma unroll
            for (int i = 0; i < 4; ++i) {
                uint4 v = *(const uint4*)(Ab + i * (16 * 256) + ks * 32);
                float f0 = fmaxf(bflo(v.x) * c0.x + c0.y, 0.f);
                float f1 = fmaxf(bfhi(v.x) * c1.x + c1.y, 0.f);
                float f2 = fmaxf(bflo(v.y) * c2.x + c2.y, 0.f);
                float f3 = fmaxf(bfhi(v.y) * c3.x + c3.y, 0.f);
                float f4 = fmaxf(bflo(v.z) * c4.x + c4.y, 0.f);
                float f5 = fmaxf(bfhi(v.z) * c5.x + c5.y, 0.f);
                float f6 = fmaxf(bflo(v.w) * c6.x + c6.y, 0.f);
                float f7 = fmaxf(bfhi(v.w) * c7.x + c7.y, 0.f);
                uint4 o;
                o.x = (uint)f2b(f0) | ((uint)f2b(f1) << 16);
                o.y = (uint)f2b(f2) | ((uint)f2b(f3) << 16);
                o.z = (uint)f2b(f4) | ((uint)f2b(f5) << 16);
                o.w = (uint)f2b(f6) | ((uint)f2b(f7) << 16);
                a[i] = *(bf16x8*)&o;
            }
        } else {
#pragma unroll
            for (int i = 0; i < 4; ++i)
                a[i] = *(const bf16x8*)(Ab + i * (16 * 256) + ks * 32);
        }
#pragma unroll
        for (int j = 0; j < 2; ++j) {
            int srow = wc * 32 + j * 16 + r;
            int idx = (srow * 256 + ko + ks * 32) ^ ((srow & 7) << 3);
            b[j] = *(const bf16x8*)(Bs + idx);
        }
#pragma unroll
        for (int i = 0; i < 4; ++i)
#pragma unroll
            for (int j = 0; j < 2; ++j)
                acc[i][j] = __builtin_amdgcn_mfma_f32_16x16x32_bf16(a[i], b[j], acc[i][j], 0, 0, 0);
    }

    int rr = (lane >> 4) * 4;   // C/D: row=(lane>>4)*4+reg, col=lane&15
    int cc = lane & 15;
#pragma unroll
    for (int i = 0; i < 4; ++i) {
        int row = m0 + wr * 64 + i * 16 + rr;
#pragma unroll
        for (int r2 = 0; r2 < 4; ++r2) {
            float dv = dinv[row + r2];
#pragma unroll
            for (int j = 0; j < 2; ++j) {
                int col = n0 + wc * 32 + j * 16 + cc;
                hs[(size_t)(row + r2) * 256 + col] = f2b(acc[i][j][r2] * dv);
            }
        }
    }
}

__global__ __launch_bounds__(512) void k_gemm_bf16(const ushort* __restrict__ A,
                                                   const ushort* __restrict__ Bt,
                                                   const float* __restrict__ dinv,
                                                   ushort* __restrict__ hs) {
    gemm_body<false>(A, Bt, dinv, nullptr, nullptr, nullptr, nullptr, hs);
}

__global__ __launch_bounds__(512) void k_gemm_bn(const ushort* __restrict__ A,
                                                 const ushort* __restrict__ Bt,
                                                 const float* __restrict__ dinv,
                                                 const float* __restrict__ bnsum,
                                                 const float* __restrict__ bnsq,
                                                 const float* __restrict__ gamma,
                                                 const float* __restrict__ beta,
                                                 ushort* __restrict__ hs) {
    gemm_body<true>(A, Bt, dinv, bnsum, bnsq, gamma, beta, hs);
}

// ---------------- CSR aggregate: 1 wave = 1 node, 2 rows per load-instruction ----------------
__global__ __launch_bounds__(256) void k_agg(const ushort* __restrict__ hs,
                                             const uint* __restrict__ csrs,
                                             const int* __restrict__ row_start,
                                             const float* __restrict__ dinv,
                                             const float* __restrict__ bias,
                                             ushort* __restrict__ aggb) {
    int wid = threadIdx.x >> 6;
    int lane = threadIdx.x & 63;
    int half = lane >> 5;
    int fq = lane & 31;
    int n = blockIdx.x * 4 + wid;

    float dv = dinv[n];
    int base = row_start[n];
    int pairs = (row_start[n + 1] - base) >> 1;

    float a0 = 0.f, a1 = 0.f, a2 = 0.f, a3 = 0.f, a4 = 0.f, a5 = 0.f, a6 = 0.f, a7 = 0.f;

    int t = 0;
    for (; t + 8 <= pairs; t += 8) {
        uint s0 = csrs[base + 2 * t + 0 + half];
        uint s1 = csrs[base + 2 * t + 2 + half];
        uint s2 = csrs[base + 2 * t + 4 + half];
        uint s3 = csrs[base + 2 * t + 6 + half];
        uint s4 = csrs[base + 2 * t + 8 + half];
        uint s5 = csrs[base + 2 * t + 10 + half];
        uint s6 = csrs[base + 2 * t + 12 + half];
        uint s7 = csrs[base + 2 * t + 14 + half];
        uint4 h0 = *(const uint4*)(hs + (size_t)s0 * 256 + fq * 8);
        uint4 h1 = *(const uint4*)(hs + (size_t)s1 * 256 + fq * 8);
        uint4 h2 = *(const uint4*)(hs + (size_t)s2 * 256 + fq * 8);
        uint4 h3 = *(const uint4*)(hs + (size_t)s3 * 256 + fq * 8);
        uint4 h4 = *(const uint4*)(hs + (size_t)s4 * 256 + fq * 8);
        uint4 h5 = *(const uint4*)(hs + (size_t)s5 * 256 + fq * 8);
        uint4 h6 = *(const uint4*)(hs + (size_t)s6 * 256 + fq * 8);
        uint4 h7 = *(const uint4*)(hs + (size_t)s7 * 256 + fq * 8);
        a0 += bflo(h0.x) + bflo(h1.x) + bflo(h2.x) + bflo(h3.x)
            + bflo(h4.x) + bflo(h5.x) + bflo(h6.x) + bflo(h7.x);
        a1 += bfhi(h0.x) + bfhi(h1.x) + bfhi(h2.x) + bfhi(h3.x)
            + bfhi(h4.x) + bfhi(h5.x) + bfhi(h6.x) + bfhi(h7.x);
        a2 += bflo(h0.y) + bflo(h1.y) + bflo(h2.y) + bflo(h3.y)
            + bflo(h4.y) + bflo(h5.y) + bflo(h6.y) + bflo(h7.y);
        a3 += bfhi(h0.y) + bfhi(h1.y) + bfhi(h2.y) + bfhi(h3.y)
            + bfhi(h4.y) + bfhi(h5.y) + bfhi(h6.y) + bfhi(h7.y);
        a4 += bflo(h0.z) + bflo(h1.z) + bflo(h2.z) + bflo(h3.z)
            + bflo(h4.z) + bflo(h5.z) + bflo(h6.z) + bflo(h7.z);
        a5 += bfhi(h0.z) + bfhi(h1.z) + bfhi(h2.z) + bfhi(h3.z)
            + bfhi(h4.z) + bfhi(h5.z) + bfhi(h6.z) + bfhi(h7.z);
        a6 += bflo(h0.w) + bflo(h1.w) + bflo(h2.w) + bflo(h3.w)
            + bflo(h4.w) + bflo(h5.w) + bflo(h6.w) + bflo(h7.w);
        a7 += bfhi(h0.w) + bfhi(h1.w) + bfhi(h2.w) + bfhi(h3.w)
            + bfhi(h4.w) + bfhi(h5.w) + bfhi(h6.w) + bfhi(h7.w);
    }
    for (; t + 2 <= pairs; t += 2) {
        uint s0 = csrs[base + 2 * t + 0 + half];
        uint s1 = csrs[base + 2 * t + 2 + half];
        uint4 h0 = *(const uint4*)(hs + (size_t)s0 * 256 + fq * 8);
        uint4 h1 = *(const uint4*)(hs + (size_t)s1 * 256 + fq * 8);
        a0 += bflo(h0.x) + bflo(h1.x);
        a1 += bfhi(h0.x) + bfhi(h1.x);
        a2 += bflo(h0.y) + bflo(h1.y);
        a3 += bfhi(h0.y) + bfhi(h1.y);
        a4 += bflo(h0.z) + bflo(h1.z);
        a5 += bfhi(h0.z) + bfhi(h1.z);
        a6 += bflo(h0.w) + bflo(h1.w);
        a7 += bfhi(h0.w) + bfhi(h1.w);
    }
    if (t < pairs) {
        uint s0 = csrs[base + 2 * t + half];
        uint4 h0 = *(const uint4*)(hs + (size_t)s0 * 256 + fq * 8);
        a0 += bflo(h0.x); a1 += bfhi(h0.x);
        a2 += bflo(h0.y); a3 += bfhi(h0.y);
        a4 += bflo(h0.z); a5 += bfhi(h0.z);
        a6 += bflo(h0.w); a7 += bfhi(h0.w);
    }

    a0 += __shfl_xor(a0, 32); a1 += __shfl_xor(a1, 32);
    a2 += __shfl_xor(a2, 32); a3 += __shfl_xor(a3, 32);
    a4 += __shfl_xor(a4, 32); a5 += __shfl_xor(a5, 32);
    a6 += __shfl_xor(a6, 32); a7 += __shfl_xor(a7, 32);

    if (half == 0) {
        float4 b0 = *(const float4*)&bias[fq * 8];
        float4 b1 = *(const float4*)&bias[fq * 8 + 4];
        float o0 = a0 * dv + b0.x, o1 = a1 * dv + b0.y;
        float o2 = a2 * dv + b0.z, o3 = a3 * dv + b0.w;
        float o4 = a4 * dv + b1.x, o5 = a5 * dv + b1.y;
        float o6 = a6 * dv + b1.z, o7 = a7 * dv + b1.w;
        uint4 ov;
        ov.x = (uint)f2b(o0) | ((uint)f2b(o1) << 16);
        ov.y = (uint)f2b(o2) | ((uint)f2b(o3) << 16);
        ov.z = (uint)f2b(o4) | ((uint)f2b(o5) << 16);
        ov.w = (uint)f2b(o6) | ((uint)f2b(o7) << 16);
        *(uint4*)(aggb + (size_t)n * HID + fq * 8) = ov;
    }
}

// ---------------- BN stats (vectorized uint4, LDS reduce) ----------------
__global__ __launch_bounds__(256) void k_bn_stats(const ushort* __restrict__ aggb,
                                                  float* __restrict__ bnsum,
                                                  float* __restrict__ bnsq) {
    int t = threadIdx.x;
    int fq = t & 31;
    int rg = t >> 5;
    int r0 = blockIdx.x * 128 + rg * 16;

    float s[8] = {}, q[8] = {};
    for (int r = 0; r < 16; ++r) {
        uint4 v = *(const uint4*)(aggb + (size_t)(r0 + r) * HID + fq * 8);
        float f0 = bflo(v.x), f1 = bfhi(v.x), f2 = bflo(v.y), f3 = bfhi(v.y);
        float f4 = bflo(v.z), f5 = bfhi(v.z), f6 = bflo(v.w), f7 = bfhi(v.w);
        s[0] += f0; q[0] += f0 * f0;  s[1] += f1; q[1] += f1 * f1;
        s[2] += f2; q[2] += f2 * f2;  s[3] += f3; q[3] += f3 * f3;
        s[4] += f4; q[4] += f4 * f4;  s[5] += f5; q[5] += f5 * f5;
        s[6] += f6; q[6] += f6 * f6;  s[7] += f7; q[7] += f7 * f7;
    }

    __shared__ float red[8][32][16];
#pragma unroll
    for (int i = 0; i < 8; ++i) {
        red[rg][fq][i] = s[i];
        red[rg][fq][8 + i] = q[i];
    }
    __syncthreads();
    int fq2 = t & 31;
    int vg = t >> 5;
#pragma unroll
    for (int k = 0; k < 2; ++k) {
        int v = vg * 2 + k;
        float acc = 0.f;
#pragma unroll
        for (int rgi = 0; rgi < 8; ++rgi) acc += red[rgi][fq2][v];
        float* dstp = (v < 8) ? bnsum : bnsq;
        atomicAdd(&dstp[fq2 * 8 + (v & 7)], acc);
    }
}

// ---------------- BN apply (layer2) + mean-pool accumulate ----------------
__global__ __launch_bounds__(256) void k_bn_pool(const ushort* __restrict__ aggb,
                                                 const float* __restrict__ bnsum,
                                                 const float* __restrict__ bnsq,
                                                 const float* __restrict__ gamma,
                                                 const float* __restrict__ beta,
                                                 float* __restrict__ pooled) {
    int g = blockIdx.x >> 4;
    int blk = blockIdx.x & 15;
    int f = threadIdx.x;
    const float invN = 1.0f / (float)N_NODES;
    float mean = bnsum[f] * invN;
    float var = bnsq[f] * invN - mean * mean;
    float sc = rsqrtf(var + BN_EPS) * gamma[f];
    float sh = beta[f] - mean * sc;
    int r0 = g * NPG + blk * 32;
    float s = 0.0f;
#pragma unroll 4
    for (int r = 0; r < 32; ++r) {
        float v = bflo((uint)aggb[(size_t)(r0 + r) * HID + f]) * sc + sh;
        s += v > 0.0f ? v : 0.0f;
    }
    atomicAdd(&pooled[g * HID + f], s);
}

// ---------------- LSTM cell + FC + log_softmax ----------------
__global__ __launch_bounds__(256) void k_head(const float* __restrict__ pooled,
                                              const float* __restrict__ W_ih,
                                              const float* __restrict__ b_ih,
                                              const float* __restrict__ b_hh,
                                              const float* __restrict__ W_fc,
                                              const float* __restrict__ b_fc,
                                              float* __restrict__ out) {
    __shared__ float p[HID];
    __shared__ float lsum[N_CLASSES][256];
    __shared__ float logits[N_CLASSES];
    int g = blockIdx.x, j = threadIdx.x;
    p[j] = pooled[g * HID + j] * (1.0f / (float)NPG);
    __syncthreads();

    float gi = 0.f, gf = 0.f, gg = 0.f, go = 0.f;
#pragma unroll 4
    for (int k = 0; k < HID; ++k) {
        float pk = p[k];
        const float* w = &W_ih[(size_t)k * (4 * HID) + j];
        gi += pk * w[0];
        gf += pk * w[HID];
        gg += pk * w[2 * HID];
        go += pk * w[3 * HID];
    }
    gi += b_ih[j] + b_hh[j];
    gf += b_ih[HID + j] + b_hh[HID + j];
    gg += b_ih[2 * HID + j] + b_hh[2 * HID + j];
    go += b_ih[3 * HID + j] + b_hh[3 * HID + j];
    (void)gf;  // c0 == 0

    float si = 1.f / (1.f + expf(-gi));
    float so = 1.f / (1.f + expf(-go));
    float c1 = si * tanhf(gg);
    float h1 = so * tanhf(c1);

    out[N_GRAPHS * N_CLASSES + g * HID + j] = h1;
    out[N_GRAPHS * N_CLASSES + N_GRAPHS * HID + g * HID + j] = c1;

#pragma unroll
    for (int c = 0; c < N_CLASSES; ++c)
        lsum[c][j] = h1 * W_fc[j * N_CLASSES + c];
    __syncthreads();
    for (int s = 128; s > 0; s >>= 1) {
        if (j < s) {
#pragma unroll
            for (int c = 0; c < N_CLASSES; ++c)
                lsum[c][j] += lsum[c][j + s];
        }
        __syncthreads();
    }
    if (j < N_CLASSES) logits[j] = lsum[j][0] + b_fc[j];
    __syncthreads();
    if (j < N_CLASSES) {
        float m = fmaxf(fmaxf(logits[0], logits[1]), fmaxf(logits[2], logits[3]));
        float lse = m + logf(expf(logits[0] - m) + expf(logits[1] - m) +
                             expf(logits[2] - m) + expf(logits[3] - m));
        out[g * N_CLASSES + j] = logits[j] - lse;
    }
}

extern "C" void kernel_launch(void* const* d_in, const int* in_sizes, int n_in,
                              void* d_out, int out_size, void* d_ws, size_t ws_size,
                              hipStream_t stream) {
    const float* x    = (const float*)d_in[0];
    const int*   ei   = (const int*)d_in[1];
    const float* W1   = (const float*)d_in[3];
    const float* b1   = (const float*)d_in[4];
    const float* g1   = (const float*)d_in[5];
    const float* be1  = (const float*)d_in[6];
    const float* W2   = (const float*)d_in[7];
    const float* b2   = (const float*)d_in[8];
    const float* g2   = (const float*)d_in[9];
    const float* be2  = (const float*)d_in[10];
    const float* W_ih = (const float*)d_in[11];
    const float* b_ih = (const float*)d_in[13];
    const float* b_hh = (const float*)d_in[14];
    const float* W_fc = (const float*)d_in[15];
    const float* b_fc = (const float*)d_in[16];
    float* out = (float*)d_out;

    int E = in_sizes[1] / 2;
    const int* src = ei;
    const int* dst = ei + E;

    const size_t MAT = (size_t)N_NODES * HID;          // 8388608
    size_t SZ = ((size_t)E + 2 * N_NODES + 1023) & ~(size_t)1023;

    ushort* aggb = (ushort*)d_ws;
    ushort* xb   = aggb + MAT;
    ushort* hs   = xb + MAT;                           // prescaled GEMM output + zero row
    ushort* Wt1  = hs + MAT + 256;
    ushort* Wt2  = Wt1 + 65536;
    float*  dinv = (float*)(Wt2 + 65536);
    int*    row_start = (int*)(dinv + N_NODES);        // N_NODES+1
    int*    cursor    = row_start + N_NODES + 2;
    uint*   csrs      = (uint*)(cursor + N_NODES);     // SZ uints
    int*    blocksum  = (int*)(csrs + SZ);
    int*    degcnt = blocksum + 128;                   // zero-init region starts here
    float*  bn1sum = (float*)(degcnt + N_NODES);
    float*  bn1sq  = bn1sum + HID;
    float*  bn2sum = bn1sq + HID;
    float*  bn2sq  = bn2sum + HID;
    float*  pooled = bn2sq + HID;
    size_t zeroBytes = (size_t)N_NODES * 4 + 4 * HID * 4 + (size_t)N_GRAPHS * HID * 4;

    dim3 blk(256);
    dim3 blk512(512);
    int edgeBlocks = (E + 255) / 256;                  // 2048
    int n8blk = (int)(MAT / 8 / 256);                  // 4096
    int sentB = (int)(SZ / 1024);
    int aggBlocks = N_NODES / 4;                       // 8192
    dim3 gemmGrid(2, N_NODES / 128);                   // 512 blocks x 512 thr

    hipMemsetAsync(degcnt, 0, zeroBytes, stream);

    // structure prep
    k_count_prep<<<edgeBlocks + n8blk + 512 + sentB, blk, 0, stream>>>(
        dst, degcnt, edgeBlocks, x, xb, n8blk, W1, W2, Wt1, Wt2, csrs, E);
    k_scan1<<<N_NODES / 256, blk, 0, stream>>>(degcnt, blocksum, hs + MAT);
    k_scan3<<<N_NODES / 256, blk, 0, stream>>>(degcnt, blocksum, dinv, row_start, cursor, csrs);
    k_fill<<<edgeBlocks, blk, 0, stream>>>(src, dst, cursor, csrs, E);

    // ---- layer 1 ----
    k_gemm_bf16<<<gemmGrid, blk512, 0, stream>>>(xb, Wt1, dinv, hs);
    k_agg<<<aggBlocks, blk, 0, stream>>>(hs, csrs, row_start, dinv, b1, aggb);
    k_bn_stats<<<N_NODES / 128, blk, 0, stream>>>(aggb, bn1sum, bn1sq);

    // ---- layer 2 (BN1-apply fused into GEMM2's A-load) ----
    k_gemm_bn<<<gemmGrid, blk512, 0, stream>>>(aggb, Wt2, dinv, bn1sum, bn1sq, g1, be1, hs);
    k_agg<<<aggBlocks, blk, 0, stream>>>(hs, csrs, row_start, dinv, b2, aggb);
    k_bn_stats<<<N_NODES / 128, blk, 0, stream>>>(aggb, bn2sum, bn2sq);

    // ---- pool + head ----
    k_bn_pool<<<N_GRAPHS * 16, blk, 0, stream>>>(aggb, bn2sum, bn2sq, g2, be2, pooled);
    k_head<<<N_GRAPHS, blk, 0, stream>>>(pooled, W_ih, b_ih, b_hh, W_fc, b_fc, out);
}

// Round 15
// 280.799 us; speedup vs baseline: 1.0432x; 1.0432x over previous
//
#include <hip/hip_runtime.h>
#include <math.h>

#define N_NODES 32768
#define N_FEAT 256
#define HID 256
#define N_GRAPHS 64
#define NPG 512
#define N_CLASSES 4
#define BN_EPS 1e-5f

typedef __attribute__((ext_vector_type(8))) short bf16x8;
typedef __attribute__((ext_vector_type(4))) float f32x4;

__device__ __forceinline__ ushort f2b(float f) {
    union { float f; uint u; } v; v.f = f;
    uint u = v.u;
    return (ushort)((u + 0x7FFFu + ((u >> 16) & 1u)) >> 16);   // RNE
}
__device__ __forceinline__ float bflo(uint u) {
    union { uint u; float f; } v; v.u = u << 16;
    return v.f;
}
__device__ __forceinline__ float bfhi(uint u) {
    union { uint u; float f; } v; v.u = u & 0xFFFF0000u;
    return v.f;
}

// ---------------- fused: degree count + x->bf16 + W transpose + csr sentinel init ----------------
__global__ void k_count_prep(const int* __restrict__ dst, int* __restrict__ degcnt, int cntB,
                             const float* __restrict__ x, ushort* __restrict__ xb, int xB,
                             const float* __restrict__ W1, const float* __restrict__ W2,
                             ushort* __restrict__ Wt1, ushort* __restrict__ Wt2,
                             uint* __restrict__ csrs, int E) {
    int b = blockIdx.x;
    int t = threadIdx.x;
    if (b < cntB) {
        int e = b * 256 + t;
        if (e < E) atomicAdd(&degcnt[dst[e]], 1);
    } else if (b < cntB + xB) {
        int i = (b - cntB) * 256 + t;
        float4 v0 = *(const float4*)(x + (size_t)i * 8);
        float4 v1 = *(const float4*)(x + (size_t)i * 8 + 4);
        uint4 o;
        o.x = (uint)f2b(v0.x) | ((uint)f2b(v0.y) << 16);
        o.y = (uint)f2b(v0.z) | ((uint)f2b(v0.w) << 16);
        o.z = (uint)f2b(v1.x) | ((uint)f2b(v1.y) << 16);
        o.w = (uint)f2b(v1.z) | ((uint)f2b(v1.w) << 16);
        *(uint4*)(xb + (size_t)i * 8) = o;
    } else if (b < cntB + xB + 512) {
        int wb = b - cntB - xB;
        const float* W = (wb < 256) ? W1 : W2;
        ushort* Wt = (wb < 256) ? Wt1 : Wt2;
        int n = wb & 255;
        Wt[n * 256 + t] = f2b(W[t * 256 + n]);
    } else {
        int i = (b - cntB - xB - 512) * 256 + t;
        uint4 s = make_uint4(N_NODES, N_NODES, N_NODES, N_NODES);
        *(uint4*)(csrs + (size_t)i * 4) = s;
    }
}

// ---------------- 2-phase scan ----------------
// phase 1: per-block (256 nodes) padded-degree sums; block 0 zeroes the pad row
__global__ __launch_bounds__(256) void k_scan1(const int* __restrict__ degcnt,
                                               int* __restrict__ blocksum,
                                               ushort* __restrict__ hs_pad) {
    int n = blockIdx.x * 256 + threadIdx.x;
    int p = (degcnt[n] + 2) & ~1;
#pragma unroll
    for (int off = 1; off < 64; off <<= 1) p += __shfl_xor(p, off);
    __shared__ int ws[4];
    int lane = threadIdx.x & 63, w = threadIdx.x >> 6;
    if (lane == 0) ws[w] = p;
    __syncthreads();
    if (threadIdx.x == 0)
        blocksum[blockIdx.x] = ws[0] + ws[1] + ws[2] + ws[3];
    if (blockIdx.x == 0 && threadIdx.x < 128)
        ((uint*)hs_pad)[threadIdx.x] = 0;
}

// phase 2: per-node run offsets (each block redundantly prefixes the 128 block sums),
// self entries, cursor, dinv, sentinel
__global__ __launch_bounds__(256) void k_scan3(const int* __restrict__ degcnt,
                                               const int* __restrict__ blocksum,
                                               float* __restrict__ dinv,
                                               int* __restrict__ row_start,
                                               int* __restrict__ cursor,
                                               uint* __restrict__ csrs) {
    __shared__ int bs[128];
    __shared__ int ws[4];
    int t = threadIdx.x;
    if (t < 128) bs[t] = blocksum[t];
    int n = blockIdx.x * 256 + t;
    int c = degcnt[n];
    int p = (c + 2) & ~1;
    int lane = t & 63, w = t >> 6;
    int inc = p;
#pragma unroll
    for (int off = 1; off < 64; off <<= 1) {
        int u = __shfl_up(inc, off);
        if (lane >= off) inc += u;
    }
    if (lane == 63) ws[w] = inc;
    __syncthreads();
    int boff = 0;
    for (int i = 0; i < blockIdx.x; ++i) boff += bs[i];   // LDS broadcast reads
    int wadd = 0;
    for (int i = 0; i < w; ++i) wadd += ws[i];
    int run = boff + wadd + inc - p;
    row_start[n] = run;
    csrs[run] = (uint)n;
    cursor[n] = run + 1;
    dinv[n] = rsqrtf((float)(c + 1));
    if (blockIdx.x == 127 && t == 255) row_start[N_NODES] = run + p;
}

// ---------------- fill CSR (append after self) ----------------
__global__ void k_fill(const int* __restrict__ src, const int* __restrict__ dst,
                       int* __restrict__ cursor, uint* __restrict__ csrs, int E) {
    int e = blockIdx.x * 256 + threadIdx.x;
    if (e >= E) return;
    int d = dst[e];
    int pos = atomicAdd(&cursor[d], 1);
    csrs[pos] = (uint)src[e];
}

// ---------------- bf16 MFMA GEMM, B staged in LDS (swizzled); optional fused BN on A ----------------
// hs[row][256] = dinv[row]*(A @ Bt^T). Block: 256 thr / 4 waves 2x2, tile 128x128. Grid (2, 256).
template <bool BN_A>
__device__ __forceinline__ void gemm_body(const ushort* __restrict__ A,
                                          const ushort* __restrict__ Bt,
                                          const float* __restrict__ dinv,
                                          const float* __restrict__ bnsum,
                                          const float* __restrict__ bnsq,
                                          const float* __restrict__ gamma,
                                          const float* __restrict__ beta,
                                          ushort* __restrict__ hs) {
    __shared__ ushort Bs[128 * 256];      // 64 KB
    __shared__ float2 bnc[256];           // 2 KB (sc, sh)
    int tid = threadIdx.x;
    int n0 = blockIdx.x * 128;
    int m0 = blockIdx.y * 128;

    if (BN_A) {
        const float invN = 1.0f / (float)N_NODES;
        float mean = bnsum[tid] * invN;
        float var = bnsq[tid] * invN - mean * mean;
        float sc = rsqrtf(var + BN_EPS) * gamma[tid];
        bnc[tid] = make_float2(sc, beta[tid] - mean * sc);
    }

#pragma unroll
    for (int c = 0; c < 16; ++c) {
        int g = c * 256 + tid;
        int idx = g * 8;
        int row = idx >> 8;
        int col = idx & 255;
        uint4 v = *(const uint4*)(Bt + (size_t)(n0 + row) * 256 + col);
        int sidx = idx ^ ((row & 7) << 3);
        *(uint4*)(Bs + sidx) = v;
    }
    __syncthreads();

    int wid = tid >> 6;
    int lane = tid & 63;
    int wr = wid >> 1, wc = wid & 1;
    int r = lane & 15;
    int ko = (lane >> 4) * 8;

    const ushort* Ab = A + (size_t)(m0 + wr * 64 + r) * 256 + ko;

    f32x4 acc[4][4] = {};
#pragma unroll
    for (int ks = 0; ks < 8; ++ks) {
        bf16x8 a[4], b[4];
        if (BN_A) {
            int kb = ko + ks * 32;
            float2 c0 = bnc[kb + 0], c1 = bnc[kb + 1], c2 = bnc[kb + 2], c3 = bnc[kb + 3];
            float2 c4 = bnc[kb + 4], c5 = bnc[kb + 5], c6 = bnc[kb + 6], c7 = bnc[kb + 7];
#pragma unroll
            for (int i = 0; i < 4; ++i) {
                uint4 v = *(const uint4*)(Ab + i * (16 * 256) + ks * 32);
                float f0 = fmaxf(bflo(v.x) * c0.x + c0.y, 0.f);
                float f1 = fmaxf(bfhi(v.x) * c1.x + c1.y, 0.f);
                float f2 = fmaxf(bflo(v.y) * c2.x + c2.y, 0.f);
                float f3 = fmaxf(bfhi(v.y) * c3.x + c3.y, 0.f);
                float f4 = fmaxf(bflo(v.z) * c4.x + c4.y, 0.f);
                float f5 = fmaxf(bfhi(v.z) * c5.x + c5.y, 0.f);
                float f6 = fmaxf(bflo(v.w) * c6.x + c6.y, 0.f);
                float f7 = fmaxf(bfhi(v.w) * c7.x + c7.y, 0.f);
                uint4 o;
                o.x = (uint)f2b(f0) | ((uint)f2b(f1) << 16);
                o.y = (uint)f2b(f2) | ((uint)f2b(f3) << 16);
                o.z = (uint)f2b(f4) | ((uint)f2b(f5) << 16);
                o.w = (uint)f2b(f6) | ((uint)f2b(f7) << 16);
                a[i] = *(bf16x8*)&o;
            }
        } else {
#pragma unroll
            for (int i = 0; i < 4; ++i)
                a[i] = *(const bf16x8*)(Ab + i * (16 * 256) + ks * 32);
        }
#pragma unroll
        for (int j = 0; j < 4; ++j) {
            int srow = wc * 64 + j * 16 + r;
            int idx = (srow * 256 + ko + ks * 32) ^ ((srow & 7) << 3);
            b[j] = *(const bf16x8*)(Bs + idx);
        }
#pragma unroll
        for (int i = 0; i < 4; ++i)
#pragma unroll
            for (int j = 0; j < 4; ++j)
                acc[i][j] = __builtin_amdgcn_mfma_f32_16x16x32_bf16(a[i], b[j], acc[i][j], 0, 0, 0);
    }

    int rr = (lane >> 4) * 4;   // C/D: row=(lane>>4)*4+reg, col=lane&15
    int cc = lane & 15;
#pragma unroll
    for (int i = 0; i < 4; ++i) {
        int row = m0 + wr * 64 + i * 16 + rr;
#pragma unroll
        for (int r2 = 0; r2 < 4; ++r2) {
            float dv = dinv[row + r2];
#pragma unroll
            for (int j = 0; j < 4; ++j) {
                int col = n0 + wc * 64 + j * 16 + cc;
                hs[(size_t)(row + r2) * 256 + col] = f2b(acc[i][j][r2] * dv);
            }
        }
    }
}

__global__ __launch_bounds__(256) void k_gemm_bf16(const ushort* __restrict__ A,
                                                   const ushort* __restrict__ Bt,
                                                   const float* __restrict__ dinv,
                                                   ushort* __restrict__ hs) {
    gemm_body<false>(A, Bt, dinv, nullptr, nullptr, nullptr, nullptr, hs);
}

__global__ __launch_bounds__(256) void k_gemm_bn(const ushort* __restrict__ A,
                                                 const ushort* __restrict__ Bt,
                                                 const float* __restrict__ dinv,
                                                 const float* __restrict__ bnsum,
                                                 const float* __restrict__ bnsq,
                                                 const float* __restrict__ gamma,
                                                 const float* __restrict__ beta,
                                                 ushort* __restrict__ hs) {
    gemm_body<true>(A, Bt, dinv, bnsum, bnsq, gamma, beta, hs);
}

// ---------------- CSR aggregate: 1 wave = 1 node, 2 rows per load-instruction ----------------
__global__ __launch_bounds__(256) void k_agg(const ushort* __restrict__ hs,
                                             const uint* __restrict__ csrs,
                                             const int* __restrict__ row_start,
                                             const float* __restrict__ dinv,
                                             const float* __restrict__ bias,
                                             ushort* __restrict__ aggb) {
    int wid = threadIdx.x >> 6;
    int lane = threadIdx.x & 63;
    int half = lane >> 5;
    int fq = lane & 31;
    int n = blockIdx.x * 4 + wid;

    float dv = dinv[n];
    int base = row_start[n];
    int pairs = (row_start[n + 1] - base) >> 1;

    float a0 = 0.f, a1 = 0.f, a2 = 0.f, a3 = 0.f, a4 = 0.f, a5 = 0.f, a6 = 0.f, a7 = 0.f;

    int t = 0;
    for (; t + 8 <= pairs; t += 8) {
        uint s0 = csrs[base + 2 * t + 0 + half];
        uint s1 = csrs[base + 2 * t + 2 + half];
        uint s2 = csrs[base + 2 * t + 4 + half];
        uint s3 = csrs[base + 2 * t + 6 + half];
        uint s4 = csrs[base + 2 * t + 8 + half];
        uint s5 = csrs[base + 2 * t + 10 + half];
        uint s6 = csrs[base + 2 * t + 12 + half];
        uint s7 = csrs[base + 2 * t + 14 + half];
        uint4 h0 = *(const uint4*)(hs + (size_t)s0 * 256 + fq * 8);
        uint4 h1 = *(const uint4*)(hs + (size_t)s1 * 256 + fq * 8);
        uint4 h2 = *(const uint4*)(hs + (size_t)s2 * 256 + fq * 8);
        uint4 h3 = *(const uint4*)(hs + (size_t)s3 * 256 + fq * 8);
        uint4 h4 = *(const uint4*)(hs + (size_t)s4 * 256 + fq * 8);
        uint4 h5 = *(const uint4*)(hs + (size_t)s5 * 256 + fq * 8);
        uint4 h6 = *(const uint4*)(hs + (size_t)s6 * 256 + fq * 8);
        uint4 h7 = *(const uint4*)(hs + (size_t)s7 * 256 + fq * 8);
        a0 += bflo(h0.x) + bflo(h1.x) + bflo(h2.x) + bflo(h3.x)
            + bflo(h4.x) + bflo(h5.x) + bflo(h6.x) + bflo(h7.x);
        a1 += bfhi(h0.x) + bfhi(h1.x) + bfhi(h2.x) + bfhi(h3.x)
            + bfhi(h4.x) + bfhi(h5.x) + bfhi(h6.x) + bfhi(h7.x);
        a2 += bflo(h0.y) + bflo(h1.y) + bflo(h2.y) + bflo(h3.y)
            + bflo(h4.y) + bflo(h5.y) + bflo(h6.y) + bflo(h7.y);
        a3 += bfhi(h0.y) + bfhi(h1.y) + bfhi(h2.y) + bfhi(h3.y)
            + bfhi(h4.y) + bfhi(h5.y) + bfhi(h6.y) + bfhi(h7.y);
        a4 += bflo(h0.z) + bflo(h1.z) + bflo(h2.z) + bflo(h3.z)
            + bflo(h4.z) + bflo(h5.z) + bflo(h6.z) + bflo(h7.z);
        a5 += bfhi(h0.z) + bfhi(h1.z) + bfhi(h2.z) + bfhi(h3.z)
            + bfhi(h4.z) + bfhi(h5.z) + bfhi(h6.z) + bfhi(h7.z);
        a6 += bflo(h0.w) + bflo(h1.w) + bflo(h2.w) + bflo(h3.w)
            + bflo(h4.w) + bflo(h5.w) + bflo(h6.w) + bflo(h7.w);
        a7 += bfhi(h0.w) + bfhi(h1.w) + bfhi(h2.w) + bfhi(h3.w)
            + bfhi(h4.w) + bfhi(h5.w) + bfhi(h6.w) + bfhi(h7.w);
    }
    for (; t + 2 <= pairs; t += 2) {
        uint s0 = csrs[base + 2 * t + 0 + half];
        uint s1 = csrs[base + 2 * t + 2 + half];
        uint4 h0 = *(const uint4*)(hs + (size_t)s0 * 256 + fq * 8);
        uint4 h1 = *(const uint4*)(hs + (size_t)s1 * 256 + fq * 8);
        a0 += bflo(h0.x) + bflo(h1.x);
        a1 += bfhi(h0.x) + bfhi(h1.x);
        a2 += bflo(h0.y) + bflo(h1.y);
        a3 += bfhi(h0.y) + bfhi(h1.y);
        a4 += bflo(h0.z) + bflo(h1.z);
        a5 += bfhi(h0.z) + bfhi(h1.z);
        a6 += bflo(h0.w) + bflo(h1.w);
        a7 += bfhi(h0.w) + bfhi(h1.w);
    }
    if (t < pairs) {
        uint s0 = csrs[base + 2 * t + half];
        uint4 h0 = *(const uint4*)(hs + (size_t)s0 * 256 + fq * 8);
        a0 += bflo(h0.x); a1 += bfhi(h0.x);
        a2 += bflo(h0.y); a3 += bfhi(h0.y);
        a4 += bflo(h0.z); a5 += bfhi(h0.z);
        a6 += bflo(h0.w); a7 += bfhi(h0.w);
    }

    a0 += __shfl_xor(a0, 32); a1 += __shfl_xor(a1, 32);
    a2 += __shfl_xor(a2, 32); a3 += __shfl_xor(a3, 32);
    a4 += __shfl_xor(a4, 32); a5 += __shfl_xor(a5, 32);
    a6 += __shfl_xor(a6, 32); a7 += __shfl_xor(a7, 32);

    if (half == 0) {
        float4 b0 = *(const float4*)&bias[fq * 8];
        float4 b1 = *(const float4*)&bias[fq * 8 + 4];
        float o0 = a0 * dv + b0.x, o1 = a1 * dv + b0.y;
        float o2 = a2 * dv + b0.z, o3 = a3 * dv + b0.w;
        float o4 = a4 * dv + b1.x, o5 = a5 * dv + b1.y;
        float o6 = a6 * dv + b1.z, o7 = a7 * dv + b1.w;
        uint4 ov;
        ov.x = (uint)f2b(o0) | ((uint)f2b(o1) << 16);
        ov.y = (uint)f2b(o2) | ((uint)f2b(o3) << 16);
        ov.z = (uint)f2b(o4) | ((uint)f2b(o5) << 16);
        ov.w = (uint)f2b(o6) | ((uint)f2b(o7) << 16);
        *(uint4*)(aggb + (size_t)n * HID + fq * 8) = ov;
    }
}

// ---------------- BN stats (vectorized uint4, LDS reduce) ----------------
__global__ __launch_bounds__(256) void k_bn_stats(const ushort* __restrict__ aggb,
                                                  float* __restrict__ bnsum,
                                                  float* __restrict__ bnsq) {
    int t = threadIdx.x;
    int fq = t & 31;
    int rg = t >> 5;
    int r0 = blockIdx.x * 128 + rg * 16;

    float s[8] = {}, q[8] = {};
    for (int r = 0; r < 16; ++r) {
        uint4 v = *(const uint4*)(aggb + (size_t)(r0 + r) * HID + fq * 8);
        float f0 = bflo(v.x), f1 = bfhi(v.x), f2 = bflo(v.y), f3 = bfhi(v.y);
        float f4 = bflo(v.z), f5 = bfhi(v.z), f6 = bflo(v.w), f7 = bfhi(v.w);
        s[0] += f0; q[0] += f0 * f0;  s[1] += f1; q[1] += f1 * f1;
        s[2] += f2; q[2] += f2 * f2;  s[3] += f3; q[3] += f3 * f3;
        s[4] += f4; q[4] += f4 * f4;  s[5] += f5; q[5] += f5 * f5;
        s[6] += f6; q[6] += f6 * f6;  s[7] += f7; q[7] += f7 * f7;
    }

    __shared__ float red[8][32][16];
#pragma unroll
    for (int i = 0; i < 8; ++i) {
        red[rg][fq][i] = s[i];
        red[rg][fq][8 + i] = q[i];
    }
    __syncthreads();
    int fq2 = t & 31;
    int vg = t >> 5;
#pragma unroll
    for (int k = 0; k < 2; ++k) {
        int v = vg * 2 + k;
        float acc = 0.f;
#pragma unroll
        for (int rgi = 0; rgi < 8; ++rgi) acc += red[rgi][fq2][v];
        float* dstp = (v < 8) ? bnsum : bnsq;
        atomicAdd(&dstp[fq2 * 8 + (v & 7)], acc);
    }
}

// ---------------- BN apply (layer2) + mean-pool accumulate ----------------
__global__ __launch_bounds__(256) void k_bn_pool(const ushort* __restrict__ aggb,
                                                 const float* __restrict__ bnsum,
                                                 const float* __restrict__ bnsq,
                                                 const float* __restrict__ gamma,
                                                 const float* __restrict__ beta,
                                                 float* __restrict__ pooled) {
    int g = blockIdx.x >> 4;
    int blk = blockIdx.x & 15;
    int f = threadIdx.x;
    const float invN = 1.0f / (float)N_NODES;
    float mean = bnsum[f] * invN;
    float var = bnsq[f] * invN - mean * mean;
    float sc = rsqrtf(var + BN_EPS) * gamma[f];
    float sh = beta[f] - mean * sc;
    int r0 = g * NPG + blk * 32;
    float s = 0.0f;
#pragma unroll 4
    for (int r = 0; r < 32; ++r) {
        float v = bflo((uint)aggb[(size_t)(r0 + r) * HID + f]) * sc + sh;
        s += v > 0.0f ? v : 0.0f;
    }
    atomicAdd(&pooled[g * HID + f], s);
}

// ---------------- LSTM cell + FC + log_softmax ----------------
__global__ __launch_bounds__(256) void k_head(const float* __restrict__ pooled,
                                              const float* __restrict__ W_ih,
                                              const float* __restrict__ b_ih,
                                              const float* __restrict__ b_hh,
                                              const float* __restrict__ W_fc,
                                              const float* __restrict__ b_fc,
                                              float* __restrict__ out) {
    __shared__ float p[HID];
    __shared__ float lsum[N_CLASSES][256];
    __shared__ float logits[N_CLASSES];
    int g = blockIdx.x, j = threadIdx.x;
    p[j] = pooled[g * HID + j] * (1.0f / (float)NPG);
    __syncthreads();

    float gi = 0.f, gf = 0.f, gg = 0.f, go = 0.f;
#pragma unroll 4
    for (int k = 0; k < HID; ++k) {
        float pk = p[k];
        const float* w = &W_ih[(size_t)k * (4 * HID) + j];
        gi += pk * w[0];
        gf += pk * w[HID];
        gg += pk * w[2 * HID];
        go += pk * w[3 * HID];
    }
    gi += b_ih[j] + b_hh[j];
    gf += b_ih[HID + j] + b_hh[HID + j];
    gg += b_ih[2 * HID + j] + b_hh[2 * HID + j];
    go += b_ih[3 * HID + j] + b_hh[3 * HID + j];
    (void)gf;  // c0 == 0

    float si = 1.f / (1.f + expf(-gi));
    float so = 1.f / (1.f + expf(-go));
    float c1 = si * tanhf(gg);
    float h1 = so * tanhf(c1);

    out[N_GRAPHS * N_CLASSES + g * HID + j] = h1;
    out[N_GRAPHS * N_CLASSES + N_GRAPHS * HID + g * HID + j] = c1;

#pragma unroll
    for (int c = 0; c < N_CLASSES; ++c)
        lsum[c][j] = h1 * W_fc[j * N_CLASSES + c];
    __syncthreads();
    for (int s = 128; s > 0; s >>= 1) {
        if (j < s) {
#pragma unroll
            for (int c = 0; c < N_CLASSES; ++c)
                lsum[c][j] += lsum[c][j + s];
        }
        __syncthreads();
    }
    if (j < N_CLASSES) logits[j] = lsum[j][0] + b_fc[j];
    __syncthreads();
    if (j < N_CLASSES) {
        float m = fmaxf(fmaxf(logits[0], logits[1]), fmaxf(logits[2], logits[3]));
        float lse = m + logf(expf(logits[0] - m) + expf(logits[1] - m) +
                             expf(logits[2] - m) + expf(logits[3] - m));
        out[g * N_CLASSES + j] = logits[j] - lse;
    }
}

extern "C" void kernel_launch(void* const* d_in, const int* in_sizes, int n_in,
                              void* d_out, int out_size, void* d_ws, size_t ws_size,
                              hipStream_t stream) {
    const float* x    = (const float*)d_in[0];
    const int*   ei   = (const int*)d_in[1];
    const float* W1   = (const float*)d_in[3];
    const float* b1   = (const float*)d_in[4];
    const float* g1   = (const float*)d_in[5];
    const float* be1  = (const float*)d_in[6];
    const float* W2   = (const float*)d_in[7];
    const float* b2   = (const float*)d_in[8];
    const float* g2   = (const float*)d_in[9];
    const float* be2  = (const float*)d_in[10];
    const float* W_ih = (const float*)d_in[11];
    const float* b_ih = (const float*)d_in[13];
    const float* b_hh = (const float*)d_in[14];
    const float* W_fc = (const float*)d_in[15];
    const float* b_fc = (const float*)d_in[16];
    float* out = (float*)d_out;

    int E = in_sizes[1] / 2;
    const int* src = ei;
    const int* dst = ei + E;

    const size_t MAT = (size_t)N_NODES * HID;          // 8388608
    size_t SZ = ((size_t)E + 2 * N_NODES + 1023) & ~(size_t)1023;

    ushort* aggb = (ushort*)d_ws;
    ushort* xb   = aggb + MAT;
    ushort* hs   = xb + MAT;                           // prescaled GEMM output + zero row
    ushort* Wt1  = hs + MAT + 256;
    ushort* Wt2  = Wt1 + 65536;
    float*  dinv = (float*)(Wt2 + 65536);
    int*    row_start = (int*)(dinv + N_NODES);        // N_NODES+1
    int*    cursor    = row_start + N_NODES + 2;
    uint*   csrs      = (uint*)(cursor + N_NODES);     // SZ uints
    int*    blocksum  = (int*)(csrs + SZ);
    int*    degcnt = blocksum + 128;                   // zero-init region starts here
    float*  bn1sum = (float*)(degcnt + N_NODES);
    float*  bn1sq  = bn1sum + HID;
    float*  bn2sum = bn1sq + HID;
    float*  bn2sq  = bn2sum + HID;
    float*  pooled = bn2sq + HID;
    size_t zeroBytes = (size_t)N_NODES * 4 + 4 * HID * 4 + (size_t)N_GRAPHS * HID * 4;

    dim3 blk(256);
    int edgeBlocks = (E + 255) / 256;                  // 2048
    int n8blk = (int)(MAT / 8 / 256);                  // 4096
    int sentB = (int)(SZ / 1024);
    int aggBlocks = N_NODES / 4;                       // 8192
    dim3 gemmGrid(2, N_NODES / 128);                   // 512 blocks x 256 thr

    hipMemsetAsync(degcnt, 0, zeroBytes, stream);

    // structure prep
    k_count_prep<<<edgeBlocks + n8blk + 512 + sentB, blk, 0, stream>>>(
        dst, degcnt, edgeBlocks, x, xb, n8blk, W1, W2, Wt1, Wt2, csrs, E);
    k_scan1<<<N_NODES / 256, blk, 0, stream>>>(degcnt, blocksum, hs + MAT);
    k_scan3<<<N_NODES / 256, blk, 0, stream>>>(degcnt, blocksum, dinv, row_start, cursor, csrs);
    k_fill<<<edgeBlocks, blk, 0, stream>>>(src, dst, cursor, csrs, E);

    // ---- layer 1 ----
    k_gemm_bf16<<<gemmGrid, blk, 0, stream>>>(xb, Wt1, dinv, hs);
    k_agg<<<aggBlocks, blk, 0, stream>>>(hs, csrs, row_start, dinv, b1, aggb);
    k_bn_stats<<<N_NODES / 128, blk, 0, stream>>>(aggb, bn1sum, bn1sq);

    // ---- layer 2 (BN1-apply fused into GEMM2's A-load) ----
    k_gemm_bn<<<gemmGrid, blk, 0, stream>>>(aggb, Wt2, dinv, bn1sum, bn1sq, g1, be1, hs);
    k_agg<<<aggBlocks, blk, 0, stream>>>(hs, csrs, row_start, dinv, b2, aggb);
    k_bn_stats<<<N_NODES / 128, blk, 0, stream>>>(aggb, bn2sum, bn2sq);

    // ---- pool + head ----
    k_bn_pool<<<N_GRAPHS * 16, blk, 0, stream>>>(aggb, bn2sum, bn2sq, g2, be2, pooled);
    k_head<<<N_GRAPHS, blk, 0, stream>>>(pooled, W_ih, b_ih, b_hh, W_fc, b_fc, out);
}